// Round 5
// baseline (356.144 us; speedup 1.0000x reference)
//
#include <hip/hip_runtime.h>
#include <cmath>

// FusionLoss = ms_ssim(fus,ir)+ms_ssim(fus,vi) + l1(max(map_ir,map_vi),fus)
//            + 10*mean(|max(|lap ir|,|lap vi|) - |lap fus||)
// Inputs: im_fus, im_ir, im_vi, map_ir, map_vi  each [32,1,512,512] fp32.
//
// d_ws layout (floats): [0..3072)    ssim partials  (3072 ssim wave-blocks)
//                       [3072..5120) l1 partials    (2048 lapl1 blocks)
//                       [5120..7168) grad partials  (2048 lapl1 blocks)
// No atomics (round-2: same-address device atomics serialize ~25ns each).
// Round-5: single-wave ssim blocks (round-4 counters showed tail-quantized
// occupancy 24% = 1024 blocks at 3-resident/CU), 42-row strips, float4 LDS
// rows (1 ds_read_b128 vs 3 ds_read_b32), rcp instead of fdiv.

struct GaussW { float w[11]; };

#define SSIM_C1 1.0e-4f
#define SSIM_C2 9.0e-4f

// ---------------- Kernel A: fused double SSIM (separable 11x11 gaussian) ----
// Grid: (8 col strips of 64, 12 row strips of 42, 32 batch) = 3072 blocks of
// ONE wave each. A wave owns 64 output columns; sweeps 52 input rows; the
// current row strip (74 cols: 64 + 10 halo) lives in a wave-private
// single-buffered LDS array of float4 {F,I,V,-}. No __syncthreads anywhere:
// DS pipe is in-order within a wave; __builtin_amdgcn_wave_barrier() fences
// the compiler from reordering the cross-lane halo write/read pairs.
// Vertical gaussian via an 11-slot register ring; slot (o mod 11) is
// OVERWRITTEN by the k=0 term when output row o begins (wipes phantom
// o<0 garbage from the 10 warm-up rows).
__global__ __launch_bounds__(64, 4)
void ssim_kernel(const float* __restrict__ fus, const float* __restrict__ irp,
                 const float* __restrict__ vip, float* __restrict__ part,
                 GaussW gw)
{
    const int b    = blockIdx.z;
    const int r0   = blockIdx.y * 42;
    const int c0   = blockIdx.x * 64;
    const int lane = threadIdx.x;                 // 0..63
    const int out_rows = min(42, 502 - r0);       // last strip: 40
    const int in_rows  = out_rows + 10;

    const size_t ib = (size_t)b * 512 * 512;
    const float* __restrict__ Fp = fus + ib;
    const float* __restrict__ Ip = irp + ib;
    const float* __restrict__ Vp = vip + ib;

    __shared__ float4 srow[80];                   // [74 used] {F,I,V,-} per col

    float w6[6];                                  // symmetric: w[k]=w[10-k]
#pragma unroll
    for (int k = 0; k < 6; ++k) w6[k] = gw.w[k];

    float acc[11][8];                             // ring: 11 rows x 8 quantities
#pragma unroll
    for (int s = 0; s < 11; ++s)
#pragma unroll
        for (int q = 0; q < 8; ++q) acc[s][q] = 0.f;

    float lssim = 0.f;
    const int  col      = c0 + lane;
    const bool col_ok   = col <= 501;             // valid output column
    const bool extra    = lane < 10;              // 10-col halo loader
    const int  col2     = c0 + 64 + lane;
    const bool extra_ok = extra && (col2 < 512);

    // prefetch input row 0
    float rf, rg, rv, rf2 = 0.f, rg2 = 0.f, rv2 = 0.f;
    {
        const size_t base = (size_t)r0 * 512 + col;
        rf = Fp[base]; rg = Ip[base]; rv = Vp[base];
        if (extra_ok) {
            const size_t b2 = (size_t)r0 * 512 + col2;
            rf2 = Fp[b2]; rg2 = Ip[b2]; rv2 = Vp[b2];
        }
    }

#pragma unroll 1
    for (int rb = 0; rb < 55; rb += 11) {
#pragma unroll
        for (int p = 0; p < 11; ++p) {
            const int r = rb + p;                 // input row within strip
            if (r < in_rows) {                    // wave-uniform guard
                // stage row r (one ds_write_b128 per lane, + halo)
                srow[lane] = make_float4(rf, rg, rv, 0.f);
                if (extra) srow[64 + lane] = make_float4(rf2, rg2, rv2, 0.f);
                __builtin_amdgcn_wave_barrier();  // fence write->read ordering

                // prefetch row r+1 (hides under compute below)
                if (r + 1 < in_rows) {
                    const size_t base = (size_t)(r0 + r + 1) * 512 + col;
                    rf = Fp[base]; rg = Ip[base]; rv = Vp[base];
                    if (extra_ok) {
                        const size_t b2 = (size_t)(r0 + r + 1) * 512 + col2;
                        rf2 = Fp[b2]; rg2 = Ip[b2]; rv2 = Vp[b2];
                    }
                }

                // horizontal gaussian sums (one ds_read_b128 per tap)
                float hf=0.f,hi=0.f,hv=0.f,hff=0.f,hii=0.f,hvv=0.f,hfi=0.f,hfv=0.f;
#pragma unroll
                for (int k = 0; k < 11; ++k) {
                    const float4 t4 = srow[lane + k];
                    const float t = w6[k < 6 ? k : 10 - k];
                    const float F = t4.x, I = t4.y, V = t4.z;
                    const float tF = t * F, tI = t * I, tV = t * V;
                    hf += tF; hi += tI; hv += tV;
                    hff = fmaf(tF, F, hff);
                    hii = fmaf(tI, I, hii);
                    hvv = fmaf(tV, V, hvv);
                    hfi = fmaf(tF, I, hfi);
                    hfv = fmaf(tF, V, hfv);
                }
                __builtin_amdgcn_wave_barrier();  // fence read->next-write

                // vertical ring: k=0 OVERWRITES slot p, k>=1 accumulates.
                acc[p][0] = w6[0] * hf;
                acc[p][1] = w6[0] * hi;
                acc[p][2] = w6[0] * hv;
                acc[p][3] = w6[0] * hff;
                acc[p][4] = w6[0] * hii;
                acc[p][5] = w6[0] * hvv;
                acc[p][6] = w6[0] * hfi;
                acc[p][7] = w6[0] * hfv;
#pragma unroll
                for (int k = 1; k < 11; ++k) {
                    const int s = (p - k + 11) % 11;   // compile-time
                    const float t = w6[k < 6 ? k : 10 - k];
                    acc[s][0] = fmaf(t, hf,  acc[s][0]);
                    acc[s][1] = fmaf(t, hi,  acc[s][1]);
                    acc[s][2] = fmaf(t, hv,  acc[s][2]);
                    acc[s][3] = fmaf(t, hff, acc[s][3]);
                    acc[s][4] = fmaf(t, hii, acc[s][4]);
                    acc[s][5] = fmaf(t, hvv, acc[s][5]);
                    acc[s][6] = fmaf(t, hfi, acc[s][6]);
                    acc[s][7] = fmaf(t, hfv, acc[s][7]);
                }
                // finalize output row r-10 (its slot just got its k=10 term)
                if (r >= 10) {
                    const int s = (p + 1) % 11;        // compile-time
                    const float mu1 = acc[s][0], mu2 = acc[s][1], mu3 = acc[s][2];
                    const float eff = acc[s][3], eii = acc[s][4], evv = acc[s][5];
                    const float efi = acc[s][6], efv = acc[s][7];
                    const float mu1sq = mu1*mu1, mu2sq = mu2*mu2, mu3sq = mu3*mu3;
                    const float mu12 = mu1*mu2, mu13 = mu1*mu3;
                    const float sf  = eff - mu1sq;
                    const float si  = eii - mu2sq;
                    const float sv  = evv - mu3sq;
                    const float s12 = efi - mu12;
                    const float s13 = efv - mu13;
                    const float n1 = (2.f*mu12 + SSIM_C1) * (2.f*s12 + SSIM_C2);
                    const float d1 = (mu1sq + mu2sq + SSIM_C1) * (sf + si + SSIM_C2);
                    const float n2 = (2.f*mu13 + SSIM_C1) * (2.f*s13 + SSIM_C2);
                    const float d2 = (mu1sq + mu3sq + SSIM_C1) * (sf + sv + SSIM_C2);
                    // v_rcp_f32 (~2^-22 rel err) vs 6.6e-2 tolerance: free
                    const float q1 = __builtin_amdgcn_rcpf(d1);
                    const float q2 = __builtin_amdgcn_rcpf(d2);
                    if (col_ok) lssim += fmaf(n1, q1, n2 * q2);
                }
            }
        }
    }

    // wave reduction -> one partial write (no atomic, no cross-wave step)
#pragma unroll
    for (int off = 32; off > 0; off >>= 1)
        lssim += __shfl_down(lssim, off);
    if (lane == 0) {
        const int blk = blockIdx.x + 8 * (blockIdx.y + 12 * blockIdx.z); // 0..3071
        part[blk] = lssim;
    }
}

// ---------------- Kernel B: L1 + laplacian grad loss ------------------------
__device__ inline float4 lap3x3(const float* __restrict__ rm,
                                const float* __restrict__ rc,
                                const float* __restrict__ rp,
                                int x0, int xl, int xr, float4& center)
{
    float4 a = *(const float4*)(rm + x0);
    float4 b = *(const float4*)(rc + x0);
    float4 c = *(const float4*)(rp + x0);
    const float aL = rm[xl], bL = rc[xl], cL = rp[xl];
    const float aR = rm[xr], bR = rc[xr], cR = rp[xr];
    const float s0 = aL + bL + cL;
    const float s1 = a.x + b.x + c.x;
    const float s2 = a.y + b.y + c.y;
    const float s3 = a.z + b.z + c.z;
    const float s4 = a.w + b.w + c.w;
    const float s5 = aR + bR + cR;
    center = b;
    float4 l;
    l.x = (s0 + s1 + s2 - 9.f*b.x) * 0.0625f;
    l.y = (s1 + s2 + s3 - 9.f*b.y) * 0.0625f;
    l.z = (s2 + s3 + s4 - 9.f*b.z) * 0.0625f;
    l.w = (s3 + s4 + s5 - 9.f*b.w) * 0.0625f;
    return l;
}

// Grid: dim3(64, 32) = 2048 blocks; each block covers 8 rows of one batch
// image (4 iterations x 2 rows). Partial sums to d_ws, no atomics.
__global__ __launch_bounds__(256, 4)
void lapl1_kernel(const float* __restrict__ fus, const float* __restrict__ irp,
                  const float* __restrict__ vip, const float* __restrict__ mir,
                  const float* __restrict__ mvi,
                  float* __restrict__ part_l1, float* __restrict__ part_gr)
{
    const int b   = blockIdx.y;
    const int tid = threadIdx.x;
    const int xq  = tid & 127;
    const int x0  = xq * 4;
    const size_t ib = (size_t)b * 512 * 512;

    const int xl = (x0 == 0)        ? 1   : x0 - 1;   // reflect padding (x)
    const int xr = (x0 + 4 == 512)  ? 510 : x0 + 4;

    const float* Fb = fus + ib;
    const float* Ib = irp + ib;
    const float* Vb = vip + ib;

    float l1s = 0.f, grs = 0.f;

#pragma unroll
    for (int it = 0; it < 4; ++it) {
        const int y  = blockIdx.x * 8 + it * 2 + (tid >> 7);
        const int ym = (y == 0)   ? 1   : y - 1;       // reflect padding (y)
        const int yp = (y == 511) ? 510 : y + 1;

        float4 cf, ci, cv;
        const float4 lf = lap3x3(Fb + (size_t)ym*512, Fb + (size_t)y*512, Fb + (size_t)yp*512, x0, xl, xr, cf);
        const float4 li = lap3x3(Ib + (size_t)ym*512, Ib + (size_t)y*512, Ib + (size_t)yp*512, x0, xl, xr, ci);
        const float4 lv = lap3x3(Vb + (size_t)ym*512, Vb + (size_t)y*512, Vb + (size_t)yp*512, x0, xl, xr, cv);

        const float4 m1 = *(const float4*)(mir + ib + (size_t)y*512 + x0);
        const float4 m2 = *(const float4*)(mvi + ib + (size_t)y*512 + x0);

        l1s += fabsf(fmaxf(m1.x, m2.x) - cf.x) + fabsf(fmaxf(m1.y, m2.y) - cf.y)
             + fabsf(fmaxf(m1.z, m2.z) - cf.z) + fabsf(fmaxf(m1.w, m2.w) - cf.w);

        grs += fabsf(fmaxf(fabsf(li.x), fabsf(lv.x)) - fabsf(lf.x))
             + fabsf(fmaxf(fabsf(li.y), fabsf(lv.y)) - fabsf(lf.y))
             + fabsf(fmaxf(fabsf(li.z), fabsf(lv.z)) - fabsf(lf.z))
             + fabsf(fmaxf(fabsf(li.w), fabsf(lv.w)) - fabsf(lf.w));
    }

#pragma unroll
    for (int off = 32; off > 0; off >>= 1) {
        l1s += __shfl_down(l1s, off);
        grs += __shfl_down(grs, off);
    }
    __shared__ float red[8];
    if ((tid & 63) == 0) { red[tid >> 6] = l1s; red[4 + (tid >> 6)] = grs; }
    __syncthreads();
    if (tid == 0) {
        const int blk = blockIdx.x + 64 * blockIdx.y;  // 0..2047
        part_l1[blk] = red[0] + red[1] + red[2] + red[3];
        part_gr[blk] = red[4] + red[5] + red[6] + red[7];
    }
}

// ---------------- final combine: reduce all partials ------------------------
__global__ void final_kernel(const float* __restrict__ ws, float* __restrict__ out)
{
    const int tid = threadIdx.x;
    float s0 = 0.f, s1 = 0.f, s2 = 0.f;
#pragma unroll
    for (int i = tid; i < 3072; i += 256) s0 += ws[i];
#pragma unroll
    for (int i = tid; i < 2048; i += 256) {
        s1 += ws[3072 + i];
        s2 += ws[5120 + i];
    }
#pragma unroll
    for (int off = 32; off > 0; off >>= 1) {
        s0 += __shfl_down(s0, off);
        s1 += __shfl_down(s1, off);
        s2 += __shfl_down(s2, off);
    }
    __shared__ float red[12];
    if ((tid & 63) == 0) {
        red[tid >> 6] = s0; red[4 + (tid >> 6)] = s1; red[8 + (tid >> 6)] = s2;
    }
    __syncthreads();
    if (tid == 0) {
        const float ssim_sum = red[0] + red[1] + red[2] + red[3];
        const float l1_sum   = red[4] + red[5] + red[6] + red[7];
        const float gr_sum   = red[8] + red[9] + red[10] + red[11];
        const float ms = 2.f - ssim_sum / 8064128.f;   // 32*502*502
        const float l1 = l1_sum / 8388608.f;           // 32*512*512
        const float gr = gr_sum / 8388608.f;
        out[0] = ms + l1 + 10.f * gr;
    }
}

extern "C" void kernel_launch(void* const* d_in, const int* in_sizes, int n_in,
                              void* d_out, int out_size, void* d_ws, size_t ws_size,
                              hipStream_t stream)
{
    const float* fus = (const float*)d_in[0];
    const float* irp = (const float*)d_in[1];
    const float* vip = (const float*)d_in[2];
    const float* mir = (const float*)d_in[3];
    const float* mvi = (const float*)d_in[4];
    float* out = (float*)d_out;
    float* ws  = (float*)d_ws;

    // gaussian window (matches np: f64 normalize, cast to f32)
    GaussW gw;
    double g[11], s = 0.0;
    for (int i = 0; i < 11; ++i) {
        const double d = (double)i - 5.0;
        g[i] = std::exp(-(d * d) / (2.0 * 1.5 * 1.5));
        s += g[i];
    }
    for (int i = 0; i < 11; ++i) gw.w[i] = (float)(g[i] / s);

    ssim_kernel<<<dim3(8, 12, 32), 64, 0, stream>>>(fus, irp, vip, ws, gw);
    lapl1_kernel<<<dim3(64, 32), 256, 0, stream>>>(fus, irp, vip, mir, mvi,
                                                   ws + 3072, ws + 5120);
    final_kernel<<<1, 256, 0, stream>>>(ws, out);
}

// Round 6
// 181.098 us; speedup vs baseline: 1.9666x; 1.9666x over previous
//
#include <hip/hip_runtime.h>
#include <cmath>

// FusionLoss = ms_ssim(fus,ir)+ms_ssim(fus,vi) + l1(max(map_ir,map_vi),fus)
//            + 10*mean(|max(|lap ir|,|lap vi|) - |lap fus||)
// Inputs: im_fus, im_ir, im_vi, map_ir, map_vi  each [32,1,512,512] fp32.
//
// d_ws layout (floats): [0..768)     ssim partials  (768 ssim blocks)
//                       [768..2816)  l1 partials    (2048 lapl1 blocks)
//                       [2816..4864) grad partials  (2048 lapl1 blocks)
//
// Journal: r2 atomics->partials (306->126us). r4 wave-private no-barrier
// ssim (88->84us, tail-quantized occupancy 24%). r5 FAILED: 64-thread
// blocks + launch_bounds(64,4) => compiler capped VGPR=64, 88-float ring
// spilled to scratch (WRITE_SIZE 925MB, 453us). r6: 256-thread blocks,
// grid = exactly 3 blocks/CU * 256 CU = 768 ssim blocks (no tail), lapl1
// fused into the same launch as backfill; keep validated float4-LDS + rcp.

struct GaussW { float w[11]; };

#define SSIM_C1 1.0e-4f
#define SSIM_C2 9.0e-4f

// ---------------- fused kernel --------------------------------------------
// blocks [0,768):   SSIM path. Block = 4 independent waves; wave wv owns 64
//   output cols of a 42-row strip; wave-private float4 LDS row {F,I,V,-};
//   no __syncthreads in the main loop (in-order DS pipe within a wave;
//   wave_barrier() fences compiler reordering). Vertical gaussian via an
//   11-slot register ring; slot (o mod 11) OVERWRITTEN at k=0 (wipes
//   phantom o<0 garbage from the 10 warm-up rows).
// blocks [768,2816): L1+laplacian path, 8 rows per block, pure streaming.
__global__ __launch_bounds__(256, 3)
void fused_kernel(const float* __restrict__ fus, const float* __restrict__ irp,
                  const float* __restrict__ vip, const float* __restrict__ mir,
                  const float* __restrict__ mvi, float* __restrict__ ws,
                  GaussW gw)
{
    const int tid = threadIdx.x;

    if (blockIdx.x < 768) {
        // ================= SSIM path =================
        const int bid  = blockIdx.x;
        const int cs   = bid & 1;            // col half
        const int rs   = (bid >> 1) % 12;    // row strip 0..11
        const int b    = bid / 24;           // batch
        const int wv   = tid >> 6;           // wave 0..3
        const int lane = tid & 63;
        const int r0   = rs * 42;
        const int c0   = cs * 256 + wv * 64; // wave's column base
        const int out_rows = min(42, 502 - r0);   // last strip: 40
        const int in_rows  = out_rows + 10;       // <= 52

        const size_t ib = (size_t)b * 512 * 512;
        const float* __restrict__ Fp = fus + ib;
        const float* __restrict__ Ip = irp + ib;
        const float* __restrict__ Vp = vip + ib;

        __shared__ float4 srow[4][80];       // wave-private {F,I,V,-} per col

        float w6[6];                         // symmetric: w[k]=w[10-k]
#pragma unroll
        for (int k = 0; k < 6; ++k) w6[k] = gw.w[k];

        float acc[11][8];                    // ring: 11 rows x 8 quantities
#pragma unroll
        for (int s = 0; s < 11; ++s)
#pragma unroll
            for (int q = 0; q < 8; ++q) acc[s][q] = 0.f;

        float lssim = 0.f;
        const int  col      = c0 + lane;
        const bool col_ok   = col <= 501;
        const bool extra    = lane < 10;     // 10-col halo loader
        const int  col2     = c0 + 64 + lane;
        const bool extra_ok = extra && (col2 < 512);

        // prefetch input row 0
        float rf, rg, rv, rf2 = 0.f, rg2 = 0.f, rv2 = 0.f;
        {
            const size_t base = (size_t)r0 * 512 + col;
            rf = Fp[base]; rg = Ip[base]; rv = Vp[base];
            if (extra_ok) {
                const size_t b2 = (size_t)r0 * 512 + col2;
                rf2 = Fp[b2]; rg2 = Ip[b2]; rv2 = Vp[b2];
            }
        }

#pragma unroll 1
        for (int rb = 0; rb < 55; rb += 11) {
#pragma unroll
            for (int p = 0; p < 11; ++p) {
                const int r = rb + p;             // input row within strip
                if (r < in_rows) {                // wave-uniform guard
                    // stage row r (ds_write_b128 per lane, + halo)
                    srow[wv][lane] = make_float4(rf, rg, rv, 0.f);
                    if (extra) srow[wv][64 + lane] = make_float4(rf2, rg2, rv2, 0.f);
                    __builtin_amdgcn_wave_barrier();  // write->read order

                    // prefetch row r+1 (hides under compute)
                    if (r + 1 < in_rows) {
                        const size_t base = (size_t)(r0 + r + 1) * 512 + col;
                        rf = Fp[base]; rg = Ip[base]; rv = Vp[base];
                        if (extra_ok) {
                            const size_t b2 = (size_t)(r0 + r + 1) * 512 + col2;
                            rf2 = Fp[b2]; rg2 = Ip[b2]; rv2 = Vp[b2];
                        }
                    }

                    // horizontal gaussian sums (ds_read_b128 per tap)
                    float hf=0.f,hi=0.f,hv=0.f,hff=0.f,hii=0.f,hvv=0.f,hfi=0.f,hfv=0.f;
#pragma unroll
                    for (int k = 0; k < 11; ++k) {
                        const float4 t4 = srow[wv][lane + k];
                        const float t = w6[k < 6 ? k : 10 - k];
                        const float F = t4.x, I = t4.y, V = t4.z;
                        const float tF = t * F, tI = t * I, tV = t * V;
                        hf += tF; hi += tI; hv += tV;
                        hff = fmaf(tF, F, hff);
                        hii = fmaf(tI, I, hii);
                        hvv = fmaf(tV, V, hvv);
                        hfi = fmaf(tF, I, hfi);
                        hfv = fmaf(tF, V, hfv);
                    }
                    __builtin_amdgcn_wave_barrier();  // read->next-write

                    // vertical ring: k=0 OVERWRITES slot p, k>=1 accumulates.
                    acc[p][0] = w6[0] * hf;
                    acc[p][1] = w6[0] * hi;
                    acc[p][2] = w6[0] * hv;
                    acc[p][3] = w6[0] * hff;
                    acc[p][4] = w6[0] * hii;
                    acc[p][5] = w6[0] * hvv;
                    acc[p][6] = w6[0] * hfi;
                    acc[p][7] = w6[0] * hfv;
#pragma unroll
                    for (int k = 1; k < 11; ++k) {
                        const int s = (p - k + 11) % 11;   // compile-time
                        const float t = w6[k < 6 ? k : 10 - k];
                        acc[s][0] = fmaf(t, hf,  acc[s][0]);
                        acc[s][1] = fmaf(t, hi,  acc[s][1]);
                        acc[s][2] = fmaf(t, hv,  acc[s][2]);
                        acc[s][3] = fmaf(t, hff, acc[s][3]);
                        acc[s][4] = fmaf(t, hii, acc[s][4]);
                        acc[s][5] = fmaf(t, hvv, acc[s][5]);
                        acc[s][6] = fmaf(t, hfi, acc[s][6]);
                        acc[s][7] = fmaf(t, hfv, acc[s][7]);
                    }
                    // finalize output row r-10
                    if (r >= 10) {
                        const int s = (p + 1) % 11;        // compile-time
                        const float mu1 = acc[s][0], mu2 = acc[s][1], mu3 = acc[s][2];
                        const float eff = acc[s][3], eii = acc[s][4], evv = acc[s][5];
                        const float efi = acc[s][6], efv = acc[s][7];
                        const float mu1sq = mu1*mu1, mu2sq = mu2*mu2, mu3sq = mu3*mu3;
                        const float mu12 = mu1*mu2, mu13 = mu1*mu3;
                        const float sf  = eff - mu1sq;
                        const float si  = eii - mu2sq;
                        const float sv  = evv - mu3sq;
                        const float s12 = efi - mu12;
                        const float s13 = efv - mu13;
                        const float n1 = (2.f*mu12 + SSIM_C1) * (2.f*s12 + SSIM_C2);
                        const float d1 = (mu1sq + mu2sq + SSIM_C1) * (sf + si + SSIM_C2);
                        const float n2 = (2.f*mu13 + SSIM_C1) * (2.f*s13 + SSIM_C2);
                        const float d2 = (mu1sq + mu3sq + SSIM_C1) * (sf + sv + SSIM_C2);
                        // v_rcp_f32 (~2^-22 rel err) vs 6.6e-2 tolerance
                        const float q1 = __builtin_amdgcn_rcpf(d1);
                        const float q2 = __builtin_amdgcn_rcpf(d2);
                        if (col_ok) lssim += fmaf(n1, q1, n2 * q2);
                    }
                }
            }
        }

        // cross-wave block reduction -> one partial write (no atomic)
#pragma unroll
        for (int off = 32; off > 0; off >>= 1)
            lssim += __shfl_down(lssim, off);
        __shared__ float red[4];
        if (lane == 0) red[wv] = lssim;
        __syncthreads();
        if (tid == 0)
            ws[bid] = red[0] + red[1] + red[2] + red[3];

    } else {
        // ================= L1 + laplacian path =================
        const int bid2 = blockIdx.x - 768;   // 0..2047
        const int yb   = bid2 & 63;          // row-block 0..63
        const int b    = bid2 >> 6;          // batch
        const int xq   = tid & 127;
        const int x0   = xq * 4;
        const size_t ib = (size_t)b * 512 * 512;

        const int xl = (x0 == 0)       ? 1   : x0 - 1;   // reflect (x)
        const int xr = (x0 + 4 == 512) ? 510 : x0 + 4;

        const float* Fb = fus + ib;
        const float* Ib = irp + ib;
        const float* Vb = vip + ib;

        float l1s = 0.f, grs = 0.f;

#pragma unroll
        for (int it = 0; it < 4; ++it) {
            const int y  = yb * 8 + it * 2 + (tid >> 7);
            const int ym = (y == 0)   ? 1   : y - 1;     // reflect (y)
            const int yp = (y == 511) ? 510 : y + 1;

            const float* frm = Fb + (size_t)ym*512;
            const float* frc = Fb + (size_t)y *512;
            const float* frp = Fb + (size_t)yp*512;
            const float* irm = Ib + (size_t)ym*512;
            const float* irc = Ib + (size_t)y *512;
            const float* irx = Ib + (size_t)yp*512;
            const float* vrm = Vb + (size_t)ym*512;
            const float* vrc = Vb + (size_t)y *512;
            const float* vrp = Vb + (size_t)yp*512;

            float4 fa = *(const float4*)(frm + x0);
            float4 fb4= *(const float4*)(frc + x0);
            float4 fc = *(const float4*)(frp + x0);
            float4 ia = *(const float4*)(irm + x0);
            float4 ib4= *(const float4*)(irc + x0);
            float4 ic = *(const float4*)(irx + x0);
            float4 va = *(const float4*)(vrm + x0);
            float4 vb4= *(const float4*)(vrc + x0);
            float4 vc = *(const float4*)(vrp + x0);

            const float fs0 = frm[xl]+frc[xl]+frp[xl];
            const float fs5 = frm[xr]+frc[xr]+frp[xr];
            const float is0 = irm[xl]+irc[xl]+irx[xl];
            const float is5 = irm[xr]+irc[xr]+irx[xr];
            const float vs0 = vrm[xl]+vrc[xl]+vrp[xl];
            const float vs5 = vrm[xr]+vrc[xr]+vrp[xr];

            const float fs1 = fa.x+fb4.x+fc.x, fs2 = fa.y+fb4.y+fc.y;
            const float fs3 = fa.z+fb4.z+fc.z, fs4 = fa.w+fb4.w+fc.w;
            const float is1 = ia.x+ib4.x+ic.x, is2 = ia.y+ib4.y+ic.y;
            const float is3 = ia.z+ib4.z+ic.z, is4 = ia.w+ib4.w+ic.w;
            const float vs1 = va.x+vb4.x+vc.x, vs2 = va.y+vb4.y+vc.y;
            const float vs3 = va.z+vb4.z+vc.z, vs4 = va.w+vb4.w+vc.w;

            float4 lf, li, lv;
            lf.x=(fs0+fs1+fs2-9.f*fb4.x)*0.0625f; lf.y=(fs1+fs2+fs3-9.f*fb4.y)*0.0625f;
            lf.z=(fs2+fs3+fs4-9.f*fb4.z)*0.0625f; lf.w=(fs3+fs4+fs5-9.f*fb4.w)*0.0625f;
            li.x=(is0+is1+is2-9.f*ib4.x)*0.0625f; li.y=(is1+is2+is3-9.f*ib4.y)*0.0625f;
            li.z=(is2+is3+is4-9.f*ib4.z)*0.0625f; li.w=(is3+is4+is5-9.f*ib4.w)*0.0625f;
            lv.x=(vs0+vs1+vs2-9.f*vb4.x)*0.0625f; lv.y=(vs1+vs2+vs3-9.f*vb4.y)*0.0625f;
            lv.z=(vs2+vs3+vs4-9.f*vb4.z)*0.0625f; lv.w=(vs3+vs4+vs5-9.f*vb4.w)*0.0625f;

            const float4 m1 = *(const float4*)(mir + ib + (size_t)y*512 + x0);
            const float4 m2 = *(const float4*)(mvi + ib + (size_t)y*512 + x0);

            l1s += fabsf(fmaxf(m1.x,m2.x)-fb4.x) + fabsf(fmaxf(m1.y,m2.y)-fb4.y)
                 + fabsf(fmaxf(m1.z,m2.z)-fb4.z) + fabsf(fmaxf(m1.w,m2.w)-fb4.w);

            grs += fabsf(fmaxf(fabsf(li.x),fabsf(lv.x))-fabsf(lf.x))
                 + fabsf(fmaxf(fabsf(li.y),fabsf(lv.y))-fabsf(lf.y))
                 + fabsf(fmaxf(fabsf(li.z),fabsf(lv.z))-fabsf(lf.z))
                 + fabsf(fmaxf(fabsf(li.w),fabsf(lv.w))-fabsf(lf.w));
        }

#pragma unroll
        for (int off = 32; off > 0; off >>= 1) {
            l1s += __shfl_down(l1s, off);
            grs += __shfl_down(grs, off);
        }
        __shared__ float red2[8];
        if ((tid & 63) == 0) { red2[tid >> 6] = l1s; red2[4 + (tid >> 6)] = grs; }
        __syncthreads();
        if (tid == 0) {
            ws[768 + bid2]  = red2[0] + red2[1] + red2[2] + red2[3];
            ws[2816 + bid2] = red2[4] + red2[5] + red2[6] + red2[7];
        }
    }
}

// ---------------- final combine: reduce all partials ------------------------
__global__ void final_kernel(const float* __restrict__ ws, float* __restrict__ out)
{
    const int tid = threadIdx.x;
    float s0 = 0.f, s1 = 0.f, s2 = 0.f;
#pragma unroll
    for (int i = tid; i < 768; i += 256) s0 += ws[i];
#pragma unroll
    for (int i = tid; i < 2048; i += 256) {
        s1 += ws[768 + i];
        s2 += ws[2816 + i];
    }
#pragma unroll
    for (int off = 32; off > 0; off >>= 1) {
        s0 += __shfl_down(s0, off);
        s1 += __shfl_down(s1, off);
        s2 += __shfl_down(s2, off);
    }
    __shared__ float red[12];
    if ((tid & 63) == 0) {
        red[tid >> 6] = s0; red[4 + (tid >> 6)] = s1; red[8 + (tid >> 6)] = s2;
    }
    __syncthreads();
    if (tid == 0) {
        const float ssim_sum = red[0] + red[1] + red[2] + red[3];
        const float l1_sum   = red[4] + red[5] + red[6] + red[7];
        const float gr_sum   = red[8] + red[9] + red[10] + red[11];
        const float ms = 2.f - ssim_sum / 8064128.f;   // 32*502*502
        const float l1 = l1_sum / 8388608.f;           // 32*512*512
        const float gr = gr_sum / 8388608.f;
        out[0] = ms + l1 + 10.f * gr;
    }
}

extern "C" void kernel_launch(void* const* d_in, const int* in_sizes, int n_in,
                              void* d_out, int out_size, void* d_ws, size_t ws_size,
                              hipStream_t stream)
{
    const float* fus = (const float*)d_in[0];
    const float* irp = (const float*)d_in[1];
    const float* vip = (const float*)d_in[2];
    const float* mir = (const float*)d_in[3];
    const float* mvi = (const float*)d_in[4];
    float* out = (float*)d_out;
    float* ws  = (float*)d_ws;

    // gaussian window (matches np: f64 normalize, cast to f32)
    GaussW gw;
    double g[11], s = 0.0;
    for (int i = 0; i < 11; ++i) {
        const double d = (double)i - 5.0;
        g[i] = std::exp(-(d * d) / (2.0 * 1.5 * 1.5));
        s += g[i];
    }
    for (int i = 0; i < 11; ++i) gw.w[i] = (float)(g[i] / s);

    fused_kernel<<<2816, 256, 0, stream>>>(fus, irp, vip, mir, mvi, ws, gw);
    final_kernel<<<1, 256, 0, stream>>>(ws, out);
}

// Round 7
// 115.154 us; speedup vs baseline: 3.0928x; 1.5727x over previous
//
#include <hip/hip_runtime.h>
#include <cmath>

// FusionLoss = ms_ssim(fus,ir)+ms_ssim(fus,vi) + l1(max(map_ir,map_vi),fus)
//            + 10*mean(|max(|lap ir|,|lap vi|) - |lap fus||)
// Inputs: im_fus, im_ir, im_vi, map_ir, map_vi  each [32,1,512,512] fp32.
//
// d_ws layout (floats): [0..768)     ssim partials  (768 ssim blocks)
//                       [768..2816)  l1 partials    (2048 lapl1 blocks)
//                       [2816..4864) grad partials  (2048 lapl1 blocks)
//
// Journal: r2 atomics->partials (306->126us). r4 wave-private no-barrier
// ssim, VGPR=80 NO SPILL, 84us but tail-quantized (occ 24%: 1024 blocks at
// 3/CU = 768+256 rounds). r5 FAILED: launch_bounds(64,4) capped VGPR=64,
// ring spilled (WRITE 925MB). r6 FAILED: fused branchy kernel + float4
// b128 srow reads re-introduced spill (WRITE 100MB, VALUBusy 26%).
// r7: r4's exact ssim codegen (scalar srow, separate kernels) with grid
// 768 = one full residency round (42-row strips), + rcp epilogue.
// GUARD METRICS: ssim WRITE_SIZE ~20KB, VGPR ~80. If larger: spill is back.

struct GaussW { float w[11]; };

#define SSIM_C1 1.0e-4f
#define SSIM_C2 9.0e-4f

// ---------------- Kernel A: fused double SSIM (separable 11x11 gaussian) ----
// Grid: (2 col blocks of 256, 12 row strips of 42, 32 batch) = 768 blocks
// = 3 blocks/CU x 256 CU exactly resident in ONE round (no tail).
// Block = 4 independent waves; wave wv owns 64 cols; wave-private scalar
// LDS rows (3x b32 arrays — the codegen r4 validated spill-free). No
// __syncthreads in the main loop: DS pipe is in-order within a wave;
// wave_barrier() only fences compiler reordering (zero-cost).
// Vertical gaussian via an 11-slot register ring; slot (o mod 11) is
// OVERWRITTEN by the k=0 term when output row o begins (wipes phantom
// o<0 garbage from the 10 warm-up rows).
__global__ __launch_bounds__(256, 3)
void ssim_kernel(const float* __restrict__ fus, const float* __restrict__ irp,
                 const float* __restrict__ vip, float* __restrict__ part,
                 GaussW gw)
{
    const int b    = blockIdx.z;
    const int r0   = blockIdx.y * 42;
    const int tid  = threadIdx.x;
    const int wv   = tid >> 6;          // wave 0..3
    const int lane = tid & 63;
    const int c0   = blockIdx.x * 256 + wv * 64;   // wave's column base
    const int out_rows = min(42, 502 - r0);        // last strip: 40
    const int in_rows  = out_rows + 10;            // <= 52

    const size_t ib = (size_t)b * 512 * 512;
    const float* __restrict__ Fp = fus + ib;
    const float* __restrict__ Ip = irp + ib;
    const float* __restrict__ Vp = vip + ib;

    __shared__ float srow[4][3][80];    // wave-private, single-buffered

    float w6[6];                        // gaussian symmetric: w[k]=w[10-k]
#pragma unroll
    for (int k = 0; k < 6; ++k) w6[k] = gw.w[k];

    float acc[11][8];                   // register ring: 11 rows x 8 quantities
#pragma unroll
    for (int s = 0; s < 11; ++s)
#pragma unroll
        for (int q = 0; q < 8; ++q) acc[s][q] = 0.f;

    float lssim = 0.f;
    const int  col      = c0 + lane;
    const bool col_ok   = col <= 501;             // valid output column
    const bool extra    = lane < 10;              // loads the 10-col halo
    const int  col2     = c0 + 64 + lane;
    const bool extra_ok = extra && (col2 < 512);

    // prefetch input row 0
    float rf, rg, rv, rf2 = 0.f, rg2 = 0.f, rv2 = 0.f;
    {
        const size_t base = (size_t)r0 * 512 + col;
        rf = Fp[base]; rg = Ip[base]; rv = Vp[base];
        if (extra_ok) {
            const size_t b2 = (size_t)r0 * 512 + col2;
            rf2 = Fp[b2]; rg2 = Ip[b2]; rv2 = Vp[b2];
        }
    }

#pragma unroll 1
    for (int rb = 0; rb < 55; rb += 11) {
#pragma unroll
        for (int p = 0; p < 11; ++p) {
            const int r = rb + p;                 // input row within strip
            if (r < in_rows) {                    // wave-uniform guard
                // stage row r into this wave's LDS strip
                srow[wv][0][lane] = rf;
                srow[wv][1][lane] = rg;
                srow[wv][2][lane] = rv;
                if (extra) {
                    srow[wv][0][64 + lane] = rf2;
                    srow[wv][1][64 + lane] = rg2;
                    srow[wv][2][64 + lane] = rv2;
                }
                __builtin_amdgcn_wave_barrier();  // fence write->read order

                // prefetch row r+1 (hides under compute below)
                if (r + 1 < in_rows) {
                    const size_t base = (size_t)(r0 + r + 1) * 512 + col;
                    rf = Fp[base]; rg = Ip[base]; rv = Vp[base];
                    if (extra_ok) {
                        const size_t b2 = (size_t)(r0 + r + 1) * 512 + col2;
                        rf2 = Fp[b2]; rg2 = Ip[b2]; rv2 = Vp[b2];
                    }
                }

                // horizontal gaussian sums for the 8 quantities
                float hf=0.f,hi=0.f,hv=0.f,hff=0.f,hii=0.f,hvv=0.f,hfi=0.f,hfv=0.f;
#pragma unroll
                for (int k = 0; k < 11; ++k) {
                    const float t = w6[k < 6 ? k : 10 - k];
                    const float F = srow[wv][0][lane + k];
                    const float I = srow[wv][1][lane + k];
                    const float V = srow[wv][2][lane + k];
                    const float tF = t * F, tI = t * I, tV = t * V;
                    hf += tF; hi += tI; hv += tV;
                    hff = fmaf(tF, F, hff);
                    hii = fmaf(tI, I, hii);
                    hvv = fmaf(tV, V, hvv);
                    hfi = fmaf(tF, I, hfi);
                    hfv = fmaf(tF, V, hfv);
                }
                __builtin_amdgcn_wave_barrier();  // fence read->next-write

                // vertical ring: k=0 OVERWRITES slot p, k>=1 accumulates.
                acc[p][0] = w6[0] * hf;
                acc[p][1] = w6[0] * hi;
                acc[p][2] = w6[0] * hv;
                acc[p][3] = w6[0] * hff;
                acc[p][4] = w6[0] * hii;
                acc[p][5] = w6[0] * hvv;
                acc[p][6] = w6[0] * hfi;
                acc[p][7] = w6[0] * hfv;
#pragma unroll
                for (int k = 1; k < 11; ++k) {
                    const int s = (p - k + 11) % 11;   // compile-time
                    const float t = w6[k < 6 ? k : 10 - k];
                    acc[s][0] = fmaf(t, hf,  acc[s][0]);
                    acc[s][1] = fmaf(t, hi,  acc[s][1]);
                    acc[s][2] = fmaf(t, hv,  acc[s][2]);
                    acc[s][3] = fmaf(t, hff, acc[s][3]);
                    acc[s][4] = fmaf(t, hii, acc[s][4]);
                    acc[s][5] = fmaf(t, hvv, acc[s][5]);
                    acc[s][6] = fmaf(t, hfi, acc[s][6]);
                    acc[s][7] = fmaf(t, hfv, acc[s][7]);
                }
                // finalize output row r-10 (its slot just got its k=10 term)
                if (r >= 10) {
                    const int s = (p + 1) % 11;        // compile-time
                    const float mu1 = acc[s][0], mu2 = acc[s][1], mu3 = acc[s][2];
                    const float eff = acc[s][3], eii = acc[s][4], evv = acc[s][5];
                    const float efi = acc[s][6], efv = acc[s][7];
                    const float mu1sq = mu1*mu1, mu2sq = mu2*mu2, mu3sq = mu3*mu3;
                    const float mu12 = mu1*mu2, mu13 = mu1*mu3;
                    const float sf  = eff - mu1sq;
                    const float si  = eii - mu2sq;
                    const float sv  = evv - mu3sq;
                    const float s12 = efi - mu12;
                    const float s13 = efv - mu13;
                    const float n1 = (2.f*mu12 + SSIM_C1) * (2.f*s12 + SSIM_C2);
                    const float d1 = (mu1sq + mu2sq + SSIM_C1) * (sf + si + SSIM_C2);
                    const float n2 = (2.f*mu13 + SSIM_C1) * (2.f*s13 + SSIM_C2);
                    const float d2 = (mu1sq + mu3sq + SSIM_C1) * (sf + sv + SSIM_C2);
                    // v_rcp_f32 (~2^-22 rel err) vs 6.6e-2 tolerance: free
                    const float q1 = __builtin_amdgcn_rcpf(d1);
                    const float q2 = __builtin_amdgcn_rcpf(d2);
                    if (col_ok) lssim += fmaf(n1, q1, n2 * q2);
                }
            }
        }
    }

    // cross-wave block reduction -> one partial write (no atomic)
#pragma unroll
    for (int off = 32; off > 0; off >>= 1)
        lssim += __shfl_down(lssim, off);
    __shared__ float red[4];
    if (lane == 0) red[wv] = lssim;
    __syncthreads();
    if (tid == 0) {
        const int blk = blockIdx.x + 2 * (blockIdx.y + 12 * blockIdx.z); // 0..767
        part[blk] = red[0] + red[1] + red[2] + red[3];
    }
}

// ---------------- Kernel B: L1 + laplacian grad loss ------------------------
__device__ inline float4 lap3x3(const float* __restrict__ rm,
                                const float* __restrict__ rc,
                                const float* __restrict__ rp,
                                int x0, int xl, int xr, float4& center)
{
    float4 a = *(const float4*)(rm + x0);
    float4 b = *(const float4*)(rc + x0);
    float4 c = *(const float4*)(rp + x0);
    const float aL = rm[xl], bL = rc[xl], cL = rp[xl];
    const float aR = rm[xr], bR = rc[xr], cR = rp[xr];
    const float s0 = aL + bL + cL;
    const float s1 = a.x + b.x + c.x;
    const float s2 = a.y + b.y + c.y;
    const float s3 = a.z + b.z + c.z;
    const float s4 = a.w + b.w + c.w;
    const float s5 = aR + bR + cR;
    center = b;
    float4 l;
    l.x = (s0 + s1 + s2 - 9.f*b.x) * 0.0625f;
    l.y = (s1 + s2 + s3 - 9.f*b.y) * 0.0625f;
    l.z = (s2 + s3 + s4 - 9.f*b.z) * 0.0625f;
    l.w = (s3 + s4 + s5 - 9.f*b.w) * 0.0625f;
    return l;
}

// Grid: dim3(64, 32) = 2048 blocks; each block covers 8 rows of one batch
// image (4 iterations x 2 rows). Partial sums to d_ws, no atomics.
__global__ __launch_bounds__(256, 4)
void lapl1_kernel(const float* __restrict__ fus, const float* __restrict__ irp,
                  const float* __restrict__ vip, const float* __restrict__ mir,
                  const float* __restrict__ mvi,
                  float* __restrict__ part_l1, float* __restrict__ part_gr)
{
    const int b   = blockIdx.y;
    const int tid = threadIdx.x;
    const int xq  = tid & 127;
    const int x0  = xq * 4;
    const size_t ib = (size_t)b * 512 * 512;

    const int xl = (x0 == 0)        ? 1   : x0 - 1;   // reflect padding (x)
    const int xr = (x0 + 4 == 512)  ? 510 : x0 + 4;

    const float* Fb = fus + ib;
    const float* Ib = irp + ib;
    const float* Vb = vip + ib;

    float l1s = 0.f, grs = 0.f;

#pragma unroll
    for (int it = 0; it < 4; ++it) {
        const int y  = blockIdx.x * 8 + it * 2 + (tid >> 7);
        const int ym = (y == 0)   ? 1   : y - 1;       // reflect padding (y)
        const int yp = (y == 511) ? 510 : y + 1;

        float4 cf, ci, cv;
        const float4 lf = lap3x3(Fb + (size_t)ym*512, Fb + (size_t)y*512, Fb + (size_t)yp*512, x0, xl, xr, cf);
        const float4 li = lap3x3(Ib + (size_t)ym*512, Ib + (size_t)y*512, Ib + (size_t)yp*512, x0, xl, xr, ci);
        const float4 lv = lap3x3(Vb + (size_t)ym*512, Vb + (size_t)y*512, Vb + (size_t)yp*512, x0, xl, xr, cv);

        const float4 m1 = *(const float4*)(mir + ib + (size_t)y*512 + x0);
        const float4 m2 = *(const float4*)(mvi + ib + (size_t)y*512 + x0);

        l1s += fabsf(fmaxf(m1.x, m2.x) - cf.x) + fabsf(fmaxf(m1.y, m2.y) - cf.y)
             + fabsf(fmaxf(m1.z, m2.z) - cf.z) + fabsf(fmaxf(m1.w, m2.w) - cf.w);

        grs += fabsf(fmaxf(fabsf(li.x), fabsf(lv.x)) - fabsf(lf.x))
             + fabsf(fmaxf(fabsf(li.y), fabsf(lv.y)) - fabsf(lf.y))
             + fabsf(fmaxf(fabsf(li.z), fabsf(lv.z)) - fabsf(lf.z))
             + fabsf(fmaxf(fabsf(li.w), fabsf(lv.w)) - fabsf(lf.w));
    }

#pragma unroll
    for (int off = 32; off > 0; off >>= 1) {
        l1s += __shfl_down(l1s, off);
        grs += __shfl_down(grs, off);
    }
    __shared__ float red[8];
    if ((tid & 63) == 0) { red[tid >> 6] = l1s; red[4 + (tid >> 6)] = grs; }
    __syncthreads();
    if (tid == 0) {
        const int blk = blockIdx.x + 64 * blockIdx.y;  // 0..2047
        part_l1[blk] = red[0] + red[1] + red[2] + red[3];
        part_gr[blk] = red[4] + red[5] + red[6] + red[7];
    }
}

// ---------------- final combine: reduce all partials ------------------------
__global__ void final_kernel(const float* __restrict__ ws, float* __restrict__ out)
{
    const int tid = threadIdx.x;
    float s0 = 0.f, s1 = 0.f, s2 = 0.f;
#pragma unroll
    for (int i = tid; i < 768; i += 256) s0 += ws[i];
#pragma unroll
    for (int i = tid; i < 2048; i += 256) {
        s1 += ws[768 + i];
        s2 += ws[2816 + i];
    }
#pragma unroll
    for (int off = 32; off > 0; off >>= 1) {
        s0 += __shfl_down(s0, off);
        s1 += __shfl_down(s1, off);
        s2 += __shfl_down(s2, off);
    }
    __shared__ float red[12];
    if ((tid & 63) == 0) {
        red[tid >> 6] = s0; red[4 + (tid >> 6)] = s1; red[8 + (tid >> 6)] = s2;
    }
    __syncthreads();
    if (tid == 0) {
        const float ssim_sum = red[0] + red[1] + red[2] + red[3];
        const float l1_sum   = red[4] + red[5] + red[6] + red[7];
        const float gr_sum   = red[8] + red[9] + red[10] + red[11];
        const float ms = 2.f - ssim_sum / 8064128.f;   // 32*502*502
        const float l1 = l1_sum / 8388608.f;           // 32*512*512
        const float gr = gr_sum / 8388608.f;
        out[0] = ms + l1 + 10.f * gr;
    }
}

extern "C" void kernel_launch(void* const* d_in, const int* in_sizes, int n_in,
                              void* d_out, int out_size, void* d_ws, size_t ws_size,
                              hipStream_t stream)
{
    const float* fus = (const float*)d_in[0];
    const float* irp = (const float*)d_in[1];
    const float* vip = (const float*)d_in[2];
    const float* mir = (const float*)d_in[3];
    const float* mvi = (const float*)d_in[4];
    float* out = (float*)d_out;
    float* ws  = (float*)d_ws;

    // gaussian window (matches np: f64 normalize, cast to f32)
    GaussW gw;
    double g[11], s = 0.0;
    for (int i = 0; i < 11; ++i) {
        const double d = (double)i - 5.0;
        g[i] = std::exp(-(d * d) / (2.0 * 1.5 * 1.5));
        s += g[i];
    }
    for (int i = 0; i < 11; ++i) gw.w[i] = (float)(g[i] / s);

    ssim_kernel<<<dim3(2, 12, 32), 256, 0, stream>>>(fus, irp, vip, ws, gw);
    lapl1_kernel<<<dim3(64, 32), 256, 0, stream>>>(fus, irp, vip, mir, mvi,
                                                   ws + 768, ws + 2816);
    final_kernel<<<1, 256, 0, stream>>>(ws, out);
}